// Round 1
// baseline (446.305 us; speedup 1.0000x reference)
//
#include <hip/hip_runtime.h>

#define NNODES 50000
#define NEDGES 800000

// ---------------- CSR build ----------------

__global__ void k_count(const int* __restrict__ dst, int* __restrict__ counts) {
    int e = blockIdx.x * 256 + threadIdx.x;
    if (e < NEDGES) atomicAdd(&counts[dst[e]], 1);
}

__global__ void k_dinv(const int* __restrict__ counts, float* __restrict__ dinv) {
    int i = blockIdx.x * 256 + threadIdx.x;
    if (i < NNODES) dinv[i] = rsqrtf((float)counts[i] + 1.0f);
}

__global__ void k_scan1(const int* __restrict__ counts, int* __restrict__ rowptr,
                        int* __restrict__ bsum) {
    __shared__ int s[256];
    int t = threadIdx.x, i = blockIdx.x * 256 + t;
    int v = (i < NNODES) ? counts[i] : 0;
    s[t] = v; __syncthreads();
    for (int o = 1; o < 256; o <<= 1) {
        int x = (t >= o) ? s[t - o] : 0;
        __syncthreads();
        s[t] += x;
        __syncthreads();
    }
    if (i < NNODES) rowptr[i] = s[t] - v;   // block-local exclusive
    if (t == 255) bsum[blockIdx.x] = s[255];
}

__global__ void k_scan2(int* bsum, int nb) {
    __shared__ int s[256];
    int t = threadIdx.x;
    int v = (t < nb) ? bsum[t] : 0;
    s[t] = v; __syncthreads();
    for (int o = 1; o < 256; o <<= 1) {
        int x = (t >= o) ? s[t - o] : 0;
        __syncthreads();
        s[t] += x;
        __syncthreads();
    }
    if (t < nb) bsum[t] = s[t] - v;         // exclusive block offsets
}

__global__ void k_scan3(int* __restrict__ rowptr, const int* __restrict__ bsum,
                        int* __restrict__ cursor) {
    int t = threadIdx.x, b = blockIdx.x, i = b * 256 + t;
    if (i < NNODES) {
        int r = rowptr[i] + bsum[b];
        rowptr[i] = r;
        cursor[i] = r;
    }
    if (i == 0) rowptr[NNODES] = NEDGES;
}

__global__ void k_bucket(const int* __restrict__ src, const int* __restrict__ dst,
                         int* cursor, int* __restrict__ ssrc) {
    int e = blockIdx.x * 256 + threadIdx.x;
    if (e < NEDGES) {
        int d = dst[e];
        int p = atomicAdd(&cursor[d], 1);
        ssrc[p] = src[e];
    }
}

// ---------------- GEMM: G = (A @ W) * dinv[row] ----------------
// A: M x K row-major, W: K x F row-major, G: M x F row-major.
// 64x64 tile, BK=16, 256 threads, 4x4 micro-tile per thread.

__global__ __launch_bounds__(256) void k_gemm(const float* __restrict__ A,
                                              const float* __restrict__ W,
                                              const float* __restrict__ dinv,
                                              float* __restrict__ G,
                                              int M, int K, int F) {
    __shared__ float As[16][64];
    __shared__ float Bs[16][64];
    int tid = threadIdx.x;
    int bm = blockIdx.x, bn = blockIdx.y;
    int tx = tid & 15, ty = tid >> 4;
    float acc[4][4] = {};

    int lm = tid >> 2;            // 0..63 row within A tile
    int lk = (tid & 3) * 4;       // k quad within BK
    int bkr = tid >> 4;           // 0..15 k row for B load
    int bn0 = (tid & 15) * 4;     // col quad for B load

    for (int k0 = 0; k0 < K; k0 += 16) {
        int row = bm * 64 + lm;
        float4 va = make_float4(0.f, 0.f, 0.f, 0.f);
        if (row < M) va = *(const float4*)&A[(size_t)row * K + k0 + lk];
        As[lk + 0][lm] = va.x;
        As[lk + 1][lm] = va.y;
        As[lk + 2][lm] = va.z;
        As[lk + 3][lm] = va.w;

        *(float4*)&Bs[bkr][bn0] =
            *(const float4*)&W[(size_t)(k0 + bkr) * F + bn * 64 + bn0];
        __syncthreads();

#pragma unroll
        for (int kk = 0; kk < 16; kk++) {
            float4 av = *(const float4*)&As[kk][ty * 4];
            float4 bv = *(const float4*)&Bs[kk][tx * 4];
            float a[4] = {av.x, av.y, av.z, av.w};
            float b[4] = {bv.x, bv.y, bv.z, bv.w};
#pragma unroll
            for (int i = 0; i < 4; i++)
#pragma unroll
                for (int j = 0; j < 4; j++)
                    acc[i][j] += a[i] * b[j];
        }
        __syncthreads();
    }

#pragma unroll
    for (int i = 0; i < 4; i++) {
        int row = bm * 64 + ty * 4 + i;
        if (row < M) {
            float dv = dinv[row];
            float4 o = make_float4(acc[i][0] * dv, acc[i][1] * dv,
                                   acc[i][2] * dv, acc[i][3] * dv);
            *(float4*)&G[(size_t)row * F + bn * 64 + tx * 4] = o;
        }
    }
}

// ---------------- Aggregation (pull, no atomics) ----------------
// out[n] = relu? relu(dinv[n]*(sum_{e in row n} g[ssrc[e]] + g[n]) + b)
// One thread per (node, 4-feature chunk).

__global__ __launch_bounds__(256) void k_agg(const float* __restrict__ g,
                                             const int* __restrict__ ssrc,
                                             const int* __restrict__ rowptr,
                                             const float* __restrict__ dinv,
                                             const float* __restrict__ bias,
                                             float* __restrict__ out,
                                             int F, int lgF4, int relu) {
    int gid = blockIdx.x * 256 + threadIdx.x;
    int F4 = F >> 2;
    int n = gid >> lgF4;
    if (n >= NNODES) return;
    int c4 = gid & (F4 - 1);          // float4 chunk index
    const float4* gp = (const float4*)g;

    float4 acc = gp[(size_t)n * F4 + c4];     // self term
    int e0 = rowptr[n], e1 = rowptr[n + 1];
    for (int e = e0; e < e1; e++) {
        int s = ssrc[e];
        float4 v = gp[(size_t)s * F4 + c4];
        acc.x += v.x; acc.y += v.y; acc.z += v.z; acc.w += v.w;
    }
    float dv = dinv[n];
    float4 bv = *(const float4*)&bias[c4 * 4];
    float4 o = make_float4(acc.x * dv + bv.x, acc.y * dv + bv.y,
                           acc.z * dv + bv.z, acc.w * dv + bv.w);
    if (relu) {
        o.x = fmaxf(o.x, 0.f); o.y = fmaxf(o.y, 0.f);
        o.z = fmaxf(o.z, 0.f); o.w = fmaxf(o.w, 0.f);
    }
    *(float4*)&out[(size_t)n * F + c4 * 4] = o;
}

// ---------------- launch ----------------

static inline size_t align256(size_t x) { return (x + 255) & ~(size_t)255; }

extern "C" void kernel_launch(void* const* d_in, const int* in_sizes, int n_in,
                              void* d_out, int out_size, void* d_ws, size_t ws_size,
                              hipStream_t stream) {
    const float* x  = (const float*)d_in[0];
    const int*   ei = (const int*)d_in[1];
    const float* W0 = (const float*)d_in[2];
    const float* b0 = (const float*)d_in[3];
    const float* W1 = (const float*)d_in[4];
    const float* b1 = (const float*)d_in[5];
    const float* W2 = (const float*)d_in[6];
    const float* b2 = (const float*)d_in[7];
    float* out = (float*)d_out;

    const int* src = ei;
    const int* dst = ei + NEDGES;

    // workspace layout
    char* w = (char*)d_ws;
    size_t off = 0;
    float* dinv  = (float*)(w + off); off = align256(off + NNODES * 4);
    int* counts  = (int*)(w + off);   off = align256(off + NNODES * 4);
    int* rowptr  = (int*)(w + off);   off = align256(off + (NNODES + 1) * 4);
    int* cursor  = (int*)(w + off);   off = align256(off + NNODES * 4);
    int* bsum    = (int*)(w + off);   off = align256(off + 256 * 4);
    int* ssrc    = (int*)(w + off);   off = align256(off + NEDGES * 4);
    float* bufA  = (float*)(w + off); off = align256(off + (size_t)NNODES * 128 * 4);
    float* bufB  = (float*)(w + off); off = align256(off + (size_t)NNODES * 128 * 4);

    const int EB = (NEDGES + 255) / 256;   // 3125
    const int NB = (NNODES + 255) / 256;   // 196

    // degree + CSR build
    hipMemsetAsync(counts, 0, NNODES * 4, stream);
    k_count<<<EB, 256, 0, stream>>>(dst, counts);
    k_dinv<<<NB, 256, 0, stream>>>(counts, dinv);
    k_scan1<<<NB, 256, 0, stream>>>(counts, rowptr, bsum);
    k_scan2<<<1, 256, 0, stream>>>(bsum, NB);
    k_scan3<<<NB, 256, 0, stream>>>(rowptr, bsum, cursor);
    k_bucket<<<EB, 256, 0, stream>>>(src, dst, cursor, ssrc);

    const int MB = (NNODES + 63) / 64;     // 782

    // layer 0: x(256) -> bufA g(128); agg -> bufB
    k_gemm<<<dim3(MB, 2), 256, 0, stream>>>(x, W0, dinv, bufA, NNODES, 256, 128);
    k_agg<<<(NNODES * 32) / 256, 256, 0, stream>>>(bufA, ssrc, rowptr, dinv, b0,
                                                   bufB, 128, 5, 1);
    // layer 1: bufB(128) -> bufA g(128); agg -> bufB
    k_gemm<<<dim3(MB, 2), 256, 0, stream>>>(bufB, W1, dinv, bufA, NNODES, 128, 128);
    k_agg<<<(NNODES * 32) / 256, 256, 0, stream>>>(bufA, ssrc, rowptr, dinv, b1,
                                                   bufB, 128, 5, 1);
    // layer 2: bufB(128) -> bufA g(64); agg -> d_out (no relu)
    k_gemm<<<dim3(MB, 1), 256, 0, stream>>>(bufB, W2, dinv, bufA, NNODES, 128, 64);
    k_agg<<<(NNODES * 16) / 256, 256, 0, stream>>>(bufA, ssrc, rowptr, dinv, b2,
                                                   out, 64, 4, 0);
    (void)in_sizes; (void)n_in; (void)out_size; (void)ws_size;
}

// Round 2
// 388.534 us; speedup vs baseline: 1.1487x; 1.1487x over previous
//
#include <hip/hip_runtime.h>

#define NNODES 50000
#define NEDGES 800000

typedef __attribute__((ext_vector_type(8))) short short8;
typedef __attribute__((ext_vector_type(4))) float floatx4;

// ---------------- CSR build ----------------

__global__ void k_count(const int* __restrict__ dst, int* __restrict__ counts) {
    int e = blockIdx.x * 256 + threadIdx.x;
    if (e < NEDGES) atomicAdd(&counts[dst[e]], 1);
}

__global__ void k_dinv(const int* __restrict__ counts, float* __restrict__ dinv) {
    int i = blockIdx.x * 256 + threadIdx.x;
    if (i < NNODES) dinv[i] = rsqrtf((float)counts[i] + 1.0f);
}

__global__ void k_scan1(const int* __restrict__ counts, int* __restrict__ rowptr,
                        int* __restrict__ bsum) {
    __shared__ int s[256];
    int t = threadIdx.x, i = blockIdx.x * 256 + t;
    int v = (i < NNODES) ? counts[i] : 0;
    s[t] = v; __syncthreads();
    for (int o = 1; o < 256; o <<= 1) {
        int x = (t >= o) ? s[t - o] : 0;
        __syncthreads();
        s[t] += x;
        __syncthreads();
    }
    if (i < NNODES) rowptr[i] = s[t] - v;
    if (t == 255) bsum[blockIdx.x] = s[255];
}

__global__ void k_scan2(int* bsum, int nb) {
    __shared__ int s[256];
    int t = threadIdx.x;
    int v = (t < nb) ? bsum[t] : 0;
    s[t] = v; __syncthreads();
    for (int o = 1; o < 256; o <<= 1) {
        int x = (t >= o) ? s[t - o] : 0;
        __syncthreads();
        s[t] += x;
        __syncthreads();
    }
    if (t < nb) bsum[t] = s[t] - v;
}

__global__ void k_scan3(int* __restrict__ rowptr, const int* __restrict__ bsum,
                        int* __restrict__ cursor) {
    int t = threadIdx.x, b = blockIdx.x, i = b * 256 + t;
    if (i < NNODES) {
        int r = rowptr[i] + bsum[b];
        rowptr[i] = r;
        cursor[i] = r;
    }
    if (i == 0) rowptr[NNODES] = NEDGES;
}

__global__ void k_bucket(const int* __restrict__ src, const int* __restrict__ dst,
                         int* cursor, int* __restrict__ ssrc) {
    int e = blockIdx.x * 256 + threadIdx.x;
    if (e < NEDGES) {
        int d = dst[e];
        int p = atomicAdd(&cursor[d], 1);
        ssrc[p] = src[e];
    }
}

// ---------------- split-bf16 helpers ----------------
// hi = truncate-to-bf16(v); lo = truncate-to-bf16(v - hi). Residual error
// ~2^-16 relative; lo*lo term dropped (~2^-16) — well under fp32-agg noise.

__device__ inline void split_bf16(float v, short& hi, short& lo) {
    unsigned u = __float_as_uint(v);
    unsigned hu = u & 0xffff0000u;
    hi = (short)(hu >> 16);
    float r = v - __uint_as_float(hu);
    lo = (short)(__float_as_uint(r) >> 16);
}

// W (K x F, row-major fp32) -> Wt_hi/Wt_lo (F x K, bf16 as short)
__global__ void k_wprep(const float* __restrict__ W, short* __restrict__ Wth,
                        short* __restrict__ Wtl, int K, int F) {
    int id = blockIdx.x * 256 + threadIdx.x;
    if (id >= K * F) return;
    int f = id / K, k = id - f * K;
    short h, l;
    split_bf16(W[(size_t)k * F + f], h, l);
    Wth[id] = h;
    Wtl[id] = l;
}

// ---------------- GEMM: G = (A @ W) * dinv[row]  (split-bf16 MFMA) --------
// A: M x K fp32 row-major. Wt: F x K bf16 hi/lo. G: M x F fp32.
// Block: 256 thr (4 waves), tile BM=128 x BN=F. Wave w: rows w*32..w*32+31.
// MFMA 16x16x32_bf16; layouts per m89/m120: A[m=lane&15][k=(lane>>4)*8+j],
// B[k=(lane>>4)*8+j][n=lane&15], D col=lane&15 row=(lane>>4)*4+reg.

template <int BN>
__global__ __launch_bounds__(256) void k_gemm_mfma(
    const float* __restrict__ A, const short* __restrict__ Wth,
    const short* __restrict__ Wtl, const float* __restrict__ dinv,
    float* __restrict__ G, int M, int K, int F) {
    constexpr int BM = 128, BK = 32, LDA = BK + 8;  // 40 shorts = 80B stride
    __shared__ short Ah[BM * LDA], Al[BM * LDA];
    __shared__ short Bh[BN * LDA], Bl[BN * LDA];

    const int tid = threadIdx.x;
    const int lane = tid & 63, w = tid >> 6;
    const int row0 = blockIdx.x * BM;
    constexpr int NT = BN / 16;

    floatx4 acc[2][NT] = {};

    const int ar = tid >> 1;          // A-stage row 0..127
    const int ac = (tid & 1) * 16;    // A-stage col 0 or 16
    const int fr = lane & 15, fq = lane >> 4;

    for (int k0 = 0; k0 < K; k0 += BK) {
        // ---- stage A (fp32 -> bf16 hi/lo) ----
        {
            int grow = row0 + ar;
            float va[16];
            if (grow < M) {
                const float4* ap = (const float4*)&A[(size_t)grow * K + k0 + ac];
#pragma unroll
                for (int q = 0; q < 4; q++) {
                    float4 t4 = ap[q];
                    va[q * 4 + 0] = t4.x; va[q * 4 + 1] = t4.y;
                    va[q * 4 + 2] = t4.z; va[q * 4 + 3] = t4.w;
                }
            } else {
#pragma unroll
                for (int i = 0; i < 16; i++) va[i] = 0.f;
            }
            short8 h0, h1, l0, l1;
#pragma unroll
            for (int i = 0; i < 8; i++) {
                short h, l;
                split_bf16(va[i], h, l);     h0[i] = h; l0[i] = l;
                split_bf16(va[8 + i], h, l); h1[i] = h; l1[i] = l;
            }
            *(short8*)&Ah[ar * LDA + ac]     = h0;
            *(short8*)&Ah[ar * LDA + ac + 8] = h1;
            *(short8*)&Al[ar * LDA + ac]     = l0;
            *(short8*)&Al[ar * LDA + ac + 8] = l1;
        }
        // ---- stage B (already bf16, n-major) ----
#pragma unroll
        for (int s = tid; s < BN * 4; s += 256) {
            int n = s >> 2, k8 = (s & 3) * 8;
            size_t go = (size_t)n * K + k0 + k8;
            *(short8*)&Bh[n * LDA + k8] = *(const short8*)&Wth[go];
            *(short8*)&Bl[n * LDA + k8] = *(const short8*)&Wtl[go];
        }
        __syncthreads();

        // ---- MFMA ----
        short8 a_h[2], a_l[2];
#pragma unroll
        for (int mt = 0; mt < 2; mt++) {
            int r = w * 32 + mt * 16 + fr;
            a_h[mt] = *(const short8*)&Ah[r * LDA + fq * 8];
            a_l[mt] = *(const short8*)&Al[r * LDA + fq * 8];
        }
#pragma unroll
        for (int nt = 0; nt < NT; nt++) {
            int n = nt * 16 + fr;
            short8 b_h = *(const short8*)&Bh[n * LDA + fq * 8];
            short8 b_l = *(const short8*)&Bl[n * LDA + fq * 8];
#pragma unroll
            for (int mt = 0; mt < 2; mt++) {
                acc[mt][nt] = __builtin_amdgcn_mfma_f32_16x16x32_bf16(
                    a_h[mt], b_h, acc[mt][nt], 0, 0, 0);
                acc[mt][nt] = __builtin_amdgcn_mfma_f32_16x16x32_bf16(
                    a_h[mt], b_l, acc[mt][nt], 0, 0, 0);
                acc[mt][nt] = __builtin_amdgcn_mfma_f32_16x16x32_bf16(
                    a_l[mt], b_h, acc[mt][nt], 0, 0, 0);
            }
        }
        __syncthreads();
    }

    // ---- epilogue: * dinv[row] ----
#pragma unroll
    for (int mt = 0; mt < 2; mt++) {
#pragma unroll
        for (int rr = 0; rr < 4; rr++) {
            int grow = row0 + w * 32 + mt * 16 + fq * 4 + rr;
            if (grow < M) {
                float dv = dinv[grow];
#pragma unroll
                for (int nt = 0; nt < NT; nt++) {
                    G[(size_t)grow * F + nt * 16 + fr] = acc[mt][nt][rr] * dv;
                }
            }
        }
    }
}

// ---------------- Aggregation (pull, no atomics) ----------------
// out[n] = maybe_relu(dinv[n]*(sum_{e in row n} g[ssrc[e]] + g[n]) + b)
// One thread per (node, float4 chunk); edge loop unrolled x4 for MLP.

__global__ __launch_bounds__(256) void k_agg(const float* __restrict__ g,
                                             const int* __restrict__ ssrc,
                                             const int* __restrict__ rowptr,
                                             const float* __restrict__ dinv,
                                             const float* __restrict__ bias,
                                             float* __restrict__ out,
                                             int F, int lgF4, int relu) {
    int gid = blockIdx.x * 256 + threadIdx.x;
    int F4 = F >> 2;
    int n = gid >> lgF4;
    if (n >= NNODES) return;
    int c4 = gid & (F4 - 1);
    const float4* gp = (const float4*)g;

    float4 a0 = gp[(size_t)n * F4 + c4];  // self term
    float4 a1 = make_float4(0.f, 0.f, 0.f, 0.f);
    float4 a2 = make_float4(0.f, 0.f, 0.f, 0.f);
    float4 a3 = make_float4(0.f, 0.f, 0.f, 0.f);
    int e0 = rowptr[n], e1 = rowptr[n + 1];
    int e = e0;
    for (; e + 4 <= e1; e += 4) {
        int s0 = ssrc[e], s1 = ssrc[e + 1], s2 = ssrc[e + 2], s3 = ssrc[e + 3];
        float4 v0 = gp[(size_t)s0 * F4 + c4];
        float4 v1 = gp[(size_t)s1 * F4 + c4];
        float4 v2 = gp[(size_t)s2 * F4 + c4];
        float4 v3 = gp[(size_t)s3 * F4 + c4];
        a0.x += v0.x; a0.y += v0.y; a0.z += v0.z; a0.w += v0.w;
        a1.x += v1.x; a1.y += v1.y; a1.z += v1.z; a1.w += v1.w;
        a2.x += v2.x; a2.y += v2.y; a2.z += v2.z; a2.w += v2.w;
        a3.x += v3.x; a3.y += v3.y; a3.z += v3.z; a3.w += v3.w;
    }
    for (; e < e1; e++) {
        int s = ssrc[e];
        float4 v = gp[(size_t)s * F4 + c4];
        a0.x += v.x; a0.y += v.y; a0.z += v.z; a0.w += v.w;
    }
    float4 acc = make_float4(a0.x + a1.x + a2.x + a3.x,
                             a0.y + a1.y + a2.y + a3.y,
                             a0.z + a1.z + a2.z + a3.z,
                             a0.w + a1.w + a2.w + a3.w);
    float dv = dinv[n];
    float4 bv = *(const float4*)&bias[c4 * 4];
    float4 o = make_float4(acc.x * dv + bv.x, acc.y * dv + bv.y,
                           acc.z * dv + bv.z, acc.w * dv + bv.w);
    if (relu) {
        o.x = fmaxf(o.x, 0.f); o.y = fmaxf(o.y, 0.f);
        o.z = fmaxf(o.z, 0.f); o.w = fmaxf(o.w, 0.f);
    }
    *(float4*)&out[(size_t)n * F + c4 * 4] = o;
}

// ---------------- launch ----------------

static inline size_t align256(size_t x) { return (x + 255) & ~(size_t)255; }

extern "C" void kernel_launch(void* const* d_in, const int* in_sizes, int n_in,
                              void* d_out, int out_size, void* d_ws, size_t ws_size,
                              hipStream_t stream) {
    const float* x  = (const float*)d_in[0];
    const int*   ei = (const int*)d_in[1];
    const float* W0 = (const float*)d_in[2];
    const float* b0 = (const float*)d_in[3];
    const float* W1 = (const float*)d_in[4];
    const float* b1 = (const float*)d_in[5];
    const float* W2 = (const float*)d_in[6];
    const float* b2 = (const float*)d_in[7];
    float* out = (float*)d_out;

    const int* src = ei;
    const int* dst = ei + NEDGES;

    char* w = (char*)d_ws;
    size_t off = 0;
    float* dinv  = (float*)(w + off); off = align256(off + NNODES * 4);
    int* counts  = (int*)(w + off);   off = align256(off + NNODES * 4);
    int* rowptr  = (int*)(w + off);   off = align256(off + (NNODES + 1) * 4);
    int* cursor  = (int*)(w + off);   off = align256(off + NNODES * 4);
    int* bsum    = (int*)(w + off);   off = align256(off + 256 * 4);
    int* ssrc    = (int*)(w + off);   off = align256(off + NEDGES * 4);
    short* W0h   = (short*)(w + off); off = align256(off + 256 * 128 * 2);
    short* W0l   = (short*)(w + off); off = align256(off + 256 * 128 * 2);
    short* W1h   = (short*)(w + off); off = align256(off + 128 * 128 * 2);
    short* W1l   = (short*)(w + off); off = align256(off + 128 * 128 * 2);
    short* W2h   = (short*)(w + off); off = align256(off + 128 * 64 * 2);
    short* W2l   = (short*)(w + off); off = align256(off + 128 * 64 * 2);
    float* bufA  = (float*)(w + off); off = align256(off + (size_t)NNODES * 128 * 4);
    float* bufB  = (float*)(w + off); off = align256(off + (size_t)NNODES * 128 * 4);

    const int EB = (NEDGES + 255) / 256;
    const int NB = (NNODES + 255) / 256;

    // weight prep (independent of CSR)
    k_wprep<<<(256 * 128 + 255) / 256, 256, 0, stream>>>(W0, W0h, W0l, 256, 128);
    k_wprep<<<(128 * 128 + 255) / 256, 256, 0, stream>>>(W1, W1h, W1l, 128, 128);
    k_wprep<<<(128 * 64 + 255) / 256, 256, 0, stream>>>(W2, W2h, W2l, 128, 64);

    // degree + CSR
    hipMemsetAsync(counts, 0, NNODES * 4, stream);
    k_count<<<EB, 256, 0, stream>>>(dst, counts);
    k_dinv<<<NB, 256, 0, stream>>>(counts, dinv);
    k_scan1<<<NB, 256, 0, stream>>>(counts, rowptr, bsum);
    k_scan2<<<1, 256, 0, stream>>>(bsum, NB);
    k_scan3<<<NB, 256, 0, stream>>>(rowptr, bsum, cursor);
    k_bucket<<<EB, 256, 0, stream>>>(src, dst, cursor, ssrc);

    const int MB = (NNODES + 127) / 128;  // 391

    // layer 0
    k_gemm_mfma<128><<<MB, 256, 0, stream>>>(x, W0h, W0l, dinv, bufA,
                                             NNODES, 256, 128);
    k_agg<<<(NNODES * 32) / 256, 256, 0, stream>>>(bufA, ssrc, rowptr, dinv, b0,
                                                   bufB, 128, 5, 1);
    // layer 1
    k_gemm_mfma<128><<<MB, 256, 0, stream>>>(bufB, W1h, W1l, dinv, bufA,
                                             NNODES, 128, 128);
    k_agg<<<(NNODES * 32) / 256, 256, 0, stream>>>(bufA, ssrc, rowptr, dinv, b1,
                                                   bufB, 128, 5, 1);
    // layer 2
    k_gemm_mfma<64><<<MB, 256, 0, stream>>>(bufB, W2h, W2l, dinv, bufA,
                                            NNODES, 128, 64);
    k_agg<<<(NNODES * 16) / 256, 256, 0, stream>>>(bufA, ssrc, rowptr, dinv, b2,
                                                   out, 64, 4, 0);
    (void)in_sizes; (void)n_in; (void)out_size; (void)ws_size;
}